// Round 16
// baseline (235.929 us; speedup 1.0000x reference)
//
#include <hip/hip_runtime.h>
#include <math.h>

namespace {

constexpr int B_ = 8, C_ = 256, H_ = 128, W_ = 192;
constexpr int HW = H_ * W_;
constexpr size_t CHW = (size_t)C_ * HW;
constexpr int TH = 8, TW = 16;          // block tile
constexpr int NTHREADS = 512;           // 8 waves, wave = h row
constexpr int KCH = 16;                 // channels per chunk (one K=16 MFMA)
constexpr int NCHUNK = C_ / KCH;        // 16
constexpr int BROWS = 16;               // staged f2 rows h0-4 .. h0+11
constexpr int BPOS = 24;                // staged f2 cols w0-4 .. w0+19 (overlapped tiles)
constexpr int POSB = 48;                // 32B data (16ch f16) + 16B pad
constexpr int ROWB = BPOS * POSB + 16;  // 1168 B = 73 16B-slots (odd -> bank spread)
constexpr int BUFB = BROWS * ROWB;      // 18688 per buffer
constexpr int LDSB = 2 * BUFB;          // 37376
constexpr int NSTG = BROWS * BPOS;      // 384 staging threads (waves 0-5)
constexpr int OSTR = 20;                // out-LDS dwords/row (4*20 % 32 != 0)
constexpr int OUTB = 81 * 4 * OSTR * 4; // 25920 (one h-half)
constexpr int BNOFF = OUTB;             // f2 norms [16][24] f32 (27456 <= 37376 OK)

typedef _Float16 f16x4 __attribute__((ext_vector_type(4)));
typedef _Float16 f16x8 __attribute__((ext_vector_type(8)));
typedef float f32x4 __attribute__((ext_vector_type(4)));
typedef _Float16 h2 __attribute__((ext_vector_type(2)));

__device__ __forceinline__ unsigned pk2(float x, float y) {
    return __builtin_bit_cast(unsigned, __builtin_amdgcn_cvt_pkrtz(x, y));
}
__device__ __forceinline__ float dot2f(unsigned a, unsigned b, float c) {
#if __has_builtin(__builtin_amdgcn_fdot2)
    return __builtin_amdgcn_fdot2(__builtin_bit_cast(h2, a),
                                  __builtin_bit_cast(h2, b), c, false);
#else
    const h2 ha = __builtin_bit_cast(h2, a), hb = __builtin_bit_cast(h2, b);
    return fmaf((float)ha.x, (float)hb.x, fmaf((float)ha.y, (float)hb.y, c));
#endif
}
__device__ __forceinline__ f32x4 mfma16(f16x4 a, f16x4 b, f32x4 c) {
#if __has_builtin(__builtin_amdgcn_mfma_f32_16x16x16f16)
    return __builtin_amdgcn_mfma_f32_16x16x16f16(a, b, c, 0, 0, 0);
#else
    const f16x8 a8 = {a[0], a[1], a[2], a[3], (_Float16)0, (_Float16)0, (_Float16)0, (_Float16)0};
    const f16x8 b8 = {b[0], b[1], b[2], b[3], (_Float16)0, (_Float16)0, (_Float16)0, (_Float16)0};
    return __builtin_amdgcn_mfma_f32_16x16x32_f16(a8, b8, c, 0, 0, 0);
#endif
}

// Raw publish barrier: drains LDS counts only; global loads stay in flight.
__device__ __forceinline__ void publish_barrier() {
    asm volatile("s_waitcnt lgkmcnt(0)" ::: "memory");
    __builtin_amdgcn_sched_barrier(0);
    __builtin_amdgcn_s_barrier();
    __builtin_amdgcn_sched_barrier(0);
}

__global__ __launch_bounds__(NTHREADS)
void local_corr_mfma(const float* __restrict__ f1g,
                     const float* __restrict__ f2g,
                     float* __restrict__ outg)
{
    __shared__ __align__(16) char lds[LDSB];

    // XCD swizzle: image = XCD id
    const int m  = blockIdx.x;          // 0..1535
    const int b  = m & 7;
    const int k  = m >> 3;              // 0..191
    const int bx = k % 12;
    const int by = k / 12;              // 0..15
    const int w0 = bx * TW, h0 = by * TH;

    const int tid  = threadIdx.x;
    const int hs   = tid >> 6;          // wave = h row 0..7
    const int lane = tid & 63;
    const int lp   = lane & 15;         // fragment pos
    const int lg   = lane >> 4;         // k-group (ch 4*lg..4*lg+3)

    // ---- B staging: threads 0..383 own one staged f2 position (sr, sp) ----
    const bool isStage = tid < NSTG;    // wave-uniform split (waves 0-5 vs 6-7)
    const int sr = tid / BPOS;          // 0..15
    const int sp = tid % BPOS;          // 0..23
    const int bgh = h0 - 4 + sr, bgw = w0 - 4 + sp;
    const bool bok = isStage && (bgh >= 0) && (bgh < H_) && (bgw >= 0) && (bgw < W_);
    const int bghc = min(max(bgh, 0), H_ - 1);
    const int bgwc = min(max(bgw, 0), W_ - 1);
    const float* bptr = f2g + (size_t)b * CHW + (size_t)bghc * W_ + bgwc;
    // ---- A direct-from-global: lane (lp,lg) owns f1[h0+hs][w0+lp], ch 4lg+j ----
    const float* aptr = f1g + (size_t)b * CHW + (size_t)(h0 + hs) * W_ + (w0 + lp)
                            + (size_t)(4 * lg) * HW;
    const int swoff = sr * ROWB + sp * POSB;

    float bvr[16], avr[4];
    float bn = 0.f, an = 0.f;
    f16x4 afrag;

    auto issue = [&]() {
        if (isStage) {
#pragma unroll
            for (int j = 0; j < 16; ++j) bvr[j] = bptr[(size_t)j * HW];
        }
#pragma unroll
        for (int j = 0; j < 4; ++j) avr[j] = aptr[(size_t)j * HW];
        bptr += (size_t)KCH * HW;
        aptr += (size_t)KCH * HW;
    };

    auto stage = [&](int buf) {
        if (isStage) {
            unsigned u[8];
#pragma unroll
            for (int q = 0; q < 8; ++q) {
                const float x = bok ? bvr[2 * q] : 0.f;
                const float y = bok ? bvr[2 * q + 1] : 0.f;
                u[q] = pk2(x, y);
                bn = dot2f(u[q], u[q], bn);
            }
            char* dst = lds + buf * BUFB + swoff;
            *reinterpret_cast<uint4*>(dst)      = make_uint4(u[0], u[1], u[2], u[3]);
            *reinterpret_cast<uint4*>(dst + 16) = make_uint4(u[4], u[5], u[6], u[7]);
        }
        const unsigned a0 = pk2(avr[0], avr[1]);
        const unsigned a1 = pk2(avr[2], avr[3]);
        an = dot2f(a0, a0, an);
        an = dot2f(a1, a1, an);
        afrag = __builtin_bit_cast(f16x4, make_uint2(a0, a1));
    };

    f32x4 acc[9][2];                    // statically indexed only (rule #20)
#pragma unroll
    for (int dy = 0; dy < 9; ++dy)
#pragma unroll
        for (int bt = 0; bt < 2; ++bt) acc[dy][bt] = (f32x4)0.f;

    const int fro = lp * POSB + lg * 8;

    auto compute = [&](int buf) {
        __builtin_amdgcn_s_setprio(1);
#pragma unroll
        for (int dy = 0; dy < 9; ++dy) {
            const char* rbase = lds + buf * BUFB + (hs + dy) * ROWB + fro;
            const f16x4 b0 = *reinterpret_cast<const f16x4*>(rbase);             // pos 0..15
            const f16x4 b1 = *reinterpret_cast<const f16x4*>(rbase + 8 * POSB);  // pos 8..23
            acc[dy][0] = mfma16(afrag, b0, acc[dy][0]);
            acc[dy][1] = mfma16(afrag, b1, acc[dy][1]);
        }
        __builtin_amdgcn_s_setprio(0);
    };

    // ---- pipeline: double-buffered LDS, ONE raw barrier per chunk,
    //      vmcnt never drained (R12-proven schedule) ----
    issue();                               // ch0 loads
    stage(0);                              // pack+write ch0
    issue();                               // ch1 loads — fly across barrier
    publish_barrier();
    for (int t = 0; t < NCHUNK; t += 2) {
        compute(0);                        // chunk t   (reads buf0)
        stage(1);                          // chunk t+1 (counted-wait its loads)
        if (t + 2 < NCHUNK) issue();       // ch t+2
        publish_barrier();                 // publish buf1; implies buf0 reads done
        compute(1);                        // chunk t+1 (reads buf1)
        if (t + 2 < NCHUNK) {
            stage(0);                      // chunk t+2 (writes buf0 — safe)
            if (t + 3 < NCHUNK) issue();   // ch t+3
        }
        publish_barrier();                 // publish buf0; implies buf1 reads done
    }

    // ---- norms (buffers dead now -> overlay) ----
    float* bnorm = reinterpret_cast<float*>(lds + BNOFF);   // [16][24]
    if (isStage) bnorm[tid] = bn;                           // tid = sr*24+sp
    an += __shfl_xor(an, 16);
    an += __shfl_xor(an, 32);                               // full norm of pos lp
    const float inv1own = 1.0f / fmaxf(sqrtf(an), 1e-12f);
    float inv1v[4];
#pragma unroll
    for (int r = 0; r < 4; ++r) inv1v[r] = __shfl(inv1own, 4 * lg + r);
    __syncthreads();

    // ---- epilogue: overlapped-tile band select; acc selected by VALUE ----
    const bool hiTile = lg >= 2;            // lane-uniform per 16-lane group
    const int pos     = lp + (hiTile ? 8 : 0);
    const size_t obase = (size_t)b * 81 * HW;
#pragma unroll
    for (int pass = 0; pass < 2; ++pass) {
        if ((hs >> 2) == pass) {
            const int h4 = hs & 3;
#pragma unroll
            for (int dy = 0; dy < 9; ++dy) {
                const float nb = bnorm[(hs + dy) * BPOS + pos];
                const float v2 = 1.0f / fmaxf(sqrtf(nb), 1e-12f);
                const f32x4 a4 = hiTile ? acc[dy][1] : acc[dy][0];   // v_cndmask x4
#pragma unroll
                for (int r = 0; r < 4; ++r) {
                    const int mw  = 4 * lg + r;            // f1 w within tile
                    const int dxi = pos - mw;              // dx + 4
                    if (dxi >= 0 && dxi <= 8) {
                        float* orow = reinterpret_cast<float*>(lds)
                                    + ((dy * 9 + dxi) * 4 + h4) * OSTR;
                        orow[mw] = a4[r] * inv1v[r] * v2;
                    }
                }
            }
        }
        __syncthreads();
        for (int s = tid; s < 81 * 4 * 4; s += NTHREADS) {
            const int od = s >> 4;
            const int rem = s & 15;
            const int h4 = rem >> 2, q = rem & 3;
            const float4 v = *reinterpret_cast<const float4*>(
                reinterpret_cast<const float*>(lds) + (od * 4 + h4) * OSTR + q * 4);
            *reinterpret_cast<float4*>(outg + obase + (size_t)od * HW +
                                       (size_t)(h0 + pass * 4 + h4) * W_ + w0 + q * 4) = v;
        }
        if (pass == 0) __syncthreads();
    }
}

} // namespace

extern "C" void kernel_launch(void* const* d_in, const int* in_sizes, int n_in,
                              void* d_out, int out_size, void* d_ws, size_t ws_size,
                              hipStream_t stream)
{
    (void)in_sizes; (void)n_in; (void)d_ws; (void)ws_size; (void)out_size;
    const float* f1 = (const float*)d_in[0];
    const float* f2 = (const float*)d_in[1];
    float* out = (float*)d_out;

    dim3 grid(1536, 1, 1);     // 8 images x 16 hb x 12 wb, XCD-chunked in kernel
    dim3 block(NTHREADS);      // 512 threads = 8 waves (wave = h row)
    local_corr_mfma<<<grid, block, 0, stream>>>(f1, f2, out);
}

// Round 17
// 157.417 us; speedup vs baseline: 1.4987x; 1.4987x over previous
//
#include <hip/hip_runtime.h>
#include <math.h>

namespace {

constexpr int B_ = 8, C_ = 256, H_ = 128, W_ = 192;
constexpr int HW = H_ * W_;
constexpr size_t CHW = (size_t)C_ * HW;
constexpr int TH = 8, TW = 16;          // block tile
constexpr int NTHREADS = 512;           // 8 waves, wave = h row
constexpr int KCH = 16;                 // channels per chunk
constexpr int NCHUNK = C_ / KCH;        // 16
constexpr int BROWS = 16;               // staged f2 rows h0-4 .. h0+11
constexpr int BPOS = 32;                // staged f2 cols w0-8 .. w0+23 (2 tiles)
constexpr int POSB = 48;                // 32B data + 16B pad (odd 16B slots)
constexpr int ROWB = BPOS * POSB;       // 1536
constexpr int BUFB = BROWS * ROWB;      // 24576 per buffer
constexpr int LDSB = 2 * BUFB;          // 49152 (double buffer)
constexpr int OSTR = 20;                // out-LDS dwords/row (4*20 % 32 != 0)
constexpr int OUTB = 81 * 4 * OSTR * 4; // 25920 (one h-half)
constexpr int BNOFF = OUTB;             // f2 norms [16][32] f32 overlay

typedef _Float16 f16x4 __attribute__((ext_vector_type(4)));
typedef _Float16 f16x8 __attribute__((ext_vector_type(8)));
typedef float f32x4 __attribute__((ext_vector_type(4)));
typedef _Float16 h2 __attribute__((ext_vector_type(2)));

__device__ __forceinline__ unsigned pk2(float x, float y) {
    return __builtin_bit_cast(unsigned, __builtin_amdgcn_cvt_pkrtz(x, y));
}
__device__ __forceinline__ float dot2f(unsigned a, unsigned b, float c) {
#if __has_builtin(__builtin_amdgcn_fdot2)
    return __builtin_amdgcn_fdot2(__builtin_bit_cast(h2, a),
                                  __builtin_bit_cast(h2, b), c, false);
#else
    const h2 ha = __builtin_bit_cast(h2, a), hb = __builtin_bit_cast(h2, b);
    return fmaf((float)ha.x, (float)hb.x, fmaf((float)ha.y, (float)hb.y, c));
#endif
}
__device__ __forceinline__ f32x4 mfma16(f16x4 a, f16x4 b, f32x4 c) {
#if __has_builtin(__builtin_amdgcn_mfma_f32_16x16x16f16)
    return __builtin_amdgcn_mfma_f32_16x16x16f16(a, b, c, 0, 0, 0);
#else
    const f16x8 a8 = {a[0], a[1], a[2], a[3], (_Float16)0, (_Float16)0, (_Float16)0, (_Float16)0};
    const f16x8 b8 = {b[0], b[1], b[2], b[3], (_Float16)0, (_Float16)0, (_Float16)0, (_Float16)0};
    return __builtin_amdgcn_mfma_f32_16x16x32_f16(a8, b8, c, 0, 0, 0);
#endif
}
// 1/max(sqrt(x),1e-12) == rsq(max(x,1e-24)) to ~1 ulp
__device__ __forceinline__ float rsq(float x) {
#if __has_builtin(__builtin_amdgcn_rsqf)
    return __builtin_amdgcn_rsqf(x);
#else
    return 1.0f / sqrtf(x);
#endif
}

// Raw publish barrier: waits ONLY lgkmcnt (LDS writes visible); leaves global
// loads in flight across the barrier (no vmcnt drain).
__device__ __forceinline__ void publish_barrier() {
    asm volatile("s_waitcnt lgkmcnt(0)" ::: "memory");
    __builtin_amdgcn_sched_barrier(0);
    __builtin_amdgcn_s_barrier();
    __builtin_amdgcn_sched_barrier(0);
}

__global__ __launch_bounds__(NTHREADS)
void local_corr_mfma(const float* __restrict__ f1g,
                     const float* __restrict__ f2g,
                     float* __restrict__ outg)
{
    __shared__ __align__(16) char lds[LDSB];

    // XCD swizzle: image = XCD id
    const int m  = blockIdx.x;          // 0..1535
    const int b  = m & 7;
    const int k  = m >> 3;              // 0..191
    const int bx = k % 12;
    const int by = k / 12;              // 0..15
    const int w0 = bx * TW, h0 = by * TH;

    const int tid  = threadIdx.x;
    const int hs   = tid >> 6;          // wave = h row 0..7
    const int lane = tid & 63;
    const int lp   = lane & 15;         // fragment pos
    const int lg   = lane >> 4;         // k-group (ch 4*lg..4*lg+3)

    // ---- B staging: thread owns one staged f2 position (sr, sc) ----
    const int sr = tid >> 5;            // 0..15
    const int sc = tid & 31;            // 0..31
    const int bgh = h0 - 4 + sr, bgw = w0 - 8 + sc;
    const bool bok = (bgh >= 0) && (bgh < H_) && (bgw >= 0) && (bgw < W_);
    const int bghc = min(max(bgh, 0), H_ - 1);
    const int bgwc = min(max(bgw, 0), W_ - 1);
    const float* bptr = f2g + (size_t)b * CHW + (size_t)bghc * W_ + bgwc;
    // ---- A direct-from-global: lane (lp,lg) owns f1[h0+hs][w0+lp], ch 4lg+j ----
    const float* aptr = f1g + (size_t)b * CHW + (size_t)(h0 + hs) * W_ + (w0 + lp)
                            + (size_t)(4 * lg) * HW;

    float bvr[16], avr[4];
    float bn = 0.f, an = 0.f;
    f16x4 afrag;

    auto issue = [&]() {
#pragma unroll
        for (int j = 0; j < 16; ++j) bvr[j] = bptr[(size_t)j * HW];
#pragma unroll
        for (int j = 0; j < 4; ++j) avr[j] = aptr[(size_t)j * HW];
        bptr += (size_t)KCH * HW;
        aptr += (size_t)KCH * HW;
    };

    auto stage = [&](int buf) {
        unsigned u[8];
#pragma unroll
        for (int q = 0; q < 8; ++q) {
            const float x = bok ? bvr[2 * q] : 0.f;
            const float y = bok ? bvr[2 * q + 1] : 0.f;
            u[q] = pk2(x, y);
            bn = dot2f(u[q], u[q], bn);
        }
        char* dst = lds + buf * BUFB + tid * POSB;
        *reinterpret_cast<uint4*>(dst)      = make_uint4(u[0], u[1], u[2], u[3]);
        *reinterpret_cast<uint4*>(dst + 16) = make_uint4(u[4], u[5], u[6], u[7]);
        const unsigned a0 = pk2(avr[0], avr[1]);
        const unsigned a1 = pk2(avr[2], avr[3]);
        an = dot2f(a0, a0, an);
        an = dot2f(a1, a1, an);
        afrag = __builtin_bit_cast(f16x4, make_uint2(a0, a1));
    };

    f32x4 acc[9][2];                    // statically indexed only
#pragma unroll
    for (int dy = 0; dy < 9; ++dy)
#pragma unroll
        for (int bt = 0; bt < 2; ++bt) acc[dy][bt] = (f32x4)0.f;

    const int fro = lp * POSB + lg * 8;

    auto compute = [&](int buf) {
        __builtin_amdgcn_s_setprio(1);
#pragma unroll
        for (int dy = 0; dy < 9; ++dy) {
            const char* rbase = lds + buf * BUFB + (hs + dy) * ROWB + fro;
            const f16x4 b0 = *reinterpret_cast<const f16x4*>(rbase);
            const f16x4 b1 = *reinterpret_cast<const f16x4*>(rbase + 16 * POSB);
            acc[dy][0] = mfma16(afrag, b0, acc[dy][0]);
            acc[dy][1] = mfma16(afrag, b1, acc[dy][1]);
        }
        __builtin_amdgcn_s_setprio(0);
    };

    // ---- pipeline: double-buffered LDS, ONE raw barrier per chunk,
    //      vmcnt never drained (R12-proven schedule) ----
    issue();                               // ch0 loads
    stage(0);                              // pack+write ch0
    issue();                               // ch1 loads — fly across barrier
    publish_barrier();
    for (int t = 0; t < NCHUNK; t += 2) {
        compute(0);                        // chunk t   (reads buf0)
        stage(1);                          // chunk t+1 (counted-wait its loads)
        if (t + 2 < NCHUNK) issue();       // ch t+2
        publish_barrier();                 // publish buf1; implies buf0 reads done
        compute(1);                        // chunk t+1 (reads buf1)
        if (t + 2 < NCHUNK) {
            stage(0);                      // chunk t+2 (writes buf0 — safe)
            if (t + 3 < NCHUNK) issue();   // ch t+3
        }
        publish_barrier();                 // publish buf0; implies buf1 reads done
    }

    // ---- norms (buffers dead now -> overlay) ----
    float* bnorm = reinterpret_cast<float*>(lds + BNOFF);   // [16][32]
    bnorm[tid] = bn;
    an += __shfl_xor(an, 16);
    an += __shfl_xor(an, 32);                               // full norm of pos lp
    const float inv1own = rsq(fmaxf(an, 1e-24f));
    __syncthreads();

    // ---- pre-scale acc by inv1 (per r) and inv2 (per dy,bt): all factors
    //      folded here; transients die immediately (VGPR peak stays in loop) ----
    {
        const float i0 = __shfl(inv1own, 4 * lg + 0);
        const float i1 = __shfl(inv1own, 4 * lg + 1);
        const float i2 = __shfl(inv1own, 4 * lg + 2);
        const float i3 = __shfl(inv1own, 4 * lg + 3);
#pragma unroll
        for (int dy = 0; dy < 9; ++dy) {
#pragma unroll
            for (int bt = 0; bt < 2; ++bt) {
                const float nb = bnorm[(hs + dy) * BPOS + bt * 16 + lp];
                const float v2 = rsq(fmaxf(nb, 1e-24f));
                acc[dy][bt][0] *= i0 * v2;
                acc[dy][bt][1] *= i1 * v2;
                acc[dy][bt][2] *= i2 * v2;
                acc[dy][bt][3] *= i3 * v2;
            }
        }
    }
    __syncthreads();   // bnorm reads done before out-LDS overlay writes

    // ---- epilogue: two h-half passes through out-LDS (R9/R12-verified) ----
    const size_t obase = (size_t)b * 81 * HW;
#pragma unroll
    for (int pass = 0; pass < 2; ++pass) {
        if ((hs >> 2) == pass) {
            const int h4 = hs & 3;
#pragma unroll
            for (int dy = 0; dy < 9; ++dy) {
#pragma unroll
                for (int bt = 0; bt < 2; ++bt) {
                    const int scol = bt * 16 + lp;                 // staged f2 col
#pragma unroll
                    for (int r = 0; r < 4; ++r) {
                        const int mw  = 4 * lg + r;                // f1 w within tile
                        const int dxi = scol - 4 - mw;             // dx + 4
                        if (dxi >= 0 && dxi <= 8) {
                            const int od = dy * 9 + dxi;
                            float* orow = reinterpret_cast<float*>(lds)
                                        + (od * 4 + h4) * OSTR;
                            orow[mw] = acc[dy][bt][r];
                        }
                    }
                }
            }
        }
        __syncthreads();
        for (int s = tid; s < 81 * 4 * 4; s += NTHREADS) {
            const int od = s >> 4;
            const int rem = s & 15;
            const int h4 = rem >> 2, q = rem & 3;
            const float4 v = *reinterpret_cast<const float4*>(
                reinterpret_cast<const float*>(lds) + (od * 4 + h4) * OSTR + q * 4);
            *reinterpret_cast<float4*>(outg + obase + (size_t)od * HW +
                                       (size_t)(h0 + pass * 4 + h4) * W_ + w0 + q * 4) = v;
        }
        if (pass == 0) __syncthreads();
    }
}

} // namespace

extern "C" void kernel_launch(void* const* d_in, const int* in_sizes, int n_in,
                              void* d_out, int out_size, void* d_ws, size_t ws_size,
                              hipStream_t stream)
{
    (void)in_sizes; (void)n_in; (void)d_ws; (void)ws_size; (void)out_size;
    const float* f1 = (const float*)d_in[0];
    const float* f2 = (const float*)d_in[1];
    float* out = (float*)d_out;

    dim3 grid(1536, 1, 1);     // 8 images x 16 hb x 12 wb, XCD-chunked in kernel
    dim3 block(NTHREADS);      // 512 threads = 8 waves (wave = h row)
    local_corr_mfma<<<grid, block, 0, stream>>>(f1, f2, out);
}

// Round 19
// 143.202 us; speedup vs baseline: 1.6475x; 1.0993x over previous
//
#include <hip/hip_runtime.h>
#include <math.h>

namespace {

constexpr int B_ = 8, C_ = 256, H_ = 128, W_ = 192;
constexpr int HW = H_ * W_;
constexpr size_t CHW = (size_t)C_ * HW;
constexpr int TH = 8, TW = 16;          // block tile
constexpr int NTHREADS = 512;           // 8 waves, wave = h row
constexpr int KCH = 16;                 // channels per chunk
constexpr int NCHUNK = C_ / KCH;        // 16
constexpr int BROWS = 16;               // staged f2 rows h0-4 .. h0+11
constexpr int BPOS = 32;                // staged f2 cols w0-8 .. w0+23 (2 tiles)
// chunk-row layout: [kg 0-3][lp 0-15][tile 0-1][8B] = 1024 B + 16 pad
constexpr int ROWB = 1040;
constexpr int BUFB = BROWS * ROWB;      // 16640 per buffer
constexpr int LDSB = 2 * BUFB;          // 33280 (double buffer)
constexpr int OSTR = 20;                // out-LDS dwords/row (R17-proven)
constexpr int OUTB = 81 * 4 * OSTR * 4; // 25920 (one h-half)
constexpr int BNOFF = OUTB;             // f2 norms [16][32] f32 (27968 < 33280)

typedef _Float16 f16x4 __attribute__((ext_vector_type(4)));
typedef _Float16 f16x8 __attribute__((ext_vector_type(8)));
typedef float f32x4 __attribute__((ext_vector_type(4)));
typedef _Float16 h2 __attribute__((ext_vector_type(2)));

__device__ __forceinline__ unsigned pk2(float x, float y) {
    return __builtin_bit_cast(unsigned, __builtin_amdgcn_cvt_pkrtz(x, y));
}
__device__ __forceinline__ float dot2f(unsigned a, unsigned b, float c) {
#if __has_builtin(__builtin_amdgcn_fdot2)
    return __builtin_amdgcn_fdot2(__builtin_bit_cast(h2, a),
                                  __builtin_bit_cast(h2, b), c, false);
#else
    const h2 ha = __builtin_bit_cast(h2, a), hb = __builtin_bit_cast(h2, b);
    return fmaf((float)ha.x, (float)hb.x, fmaf((float)ha.y, (float)hb.y, c));
#endif
}
__device__ __forceinline__ f32x4 mfma16(f16x4 a, f16x4 b, f32x4 c) {
#if __has_builtin(__builtin_amdgcn_mfma_f32_16x16x16f16)
    return __builtin_amdgcn_mfma_f32_16x16x16f16(a, b, c, 0, 0, 0);
#else
    const f16x8 a8 = {a[0], a[1], a[2], a[3], (_Float16)0, (_Float16)0, (_Float16)0, (_Float16)0};
    const f16x8 b8 = {b[0], b[1], b[2], b[3], (_Float16)0, (_Float16)0, (_Float16)0, (_Float16)0};
    return __builtin_amdgcn_mfma_f32_16x16x32_f16(a8, b8, c, 0, 0, 0);
#endif
}
// 1/max(sqrt(x),1e-12) == rsq(max(x,1e-24)) to ~1 ulp
__device__ __forceinline__ float rsq(float x) {
#if __has_builtin(__builtin_amdgcn_rsqf)
    return __builtin_amdgcn_rsqf(x);
#else
    return 1.0f / sqrtf(x);
#endif
}

// Raw publish barrier: waits ONLY lgkmcnt; global loads stay in flight.
__device__ __forceinline__ void publish_barrier() {
    asm volatile("s_waitcnt lgkmcnt(0)" ::: "memory");
    __builtin_amdgcn_sched_barrier(0);
    __builtin_amdgcn_s_barrier();
    __builtin_amdgcn_sched_barrier(0);
}

__global__ __launch_bounds__(NTHREADS)
void local_corr_mfma(const float* __restrict__ f1g,
                     const float* __restrict__ f2g,
                     float* __restrict__ outg)
{
    __shared__ __align__(16) char lds[LDSB];

    // XCD swizzle: image = XCD id
    const int m  = blockIdx.x;          // 0..1535
    const int b  = m & 7;
    const int k  = m >> 3;              // 0..191
    const int bx = k % 12;
    const int by = k / 12;              // 0..15
    const int w0 = bx * TW, h0 = by * TH;

    const int tid  = threadIdx.x;
    const int hs   = tid >> 6;          // wave = h row 0..7
    const int lane = tid & 63;
    const int lp   = lane & 15;         // fragment pos
    const int lg   = lane >> 4;         // k-group (ch 4*lg..4*lg+3)

    // ---- B staging: thread owns one staged f2 position (sr, sc) ----
    const int sr = tid >> 5;            // 0..15
    const int sc = tid & 31;            // 0..31
    const int bgh = h0 - 4 + sr, bgw = w0 - 8 + sc;
    const bool bok = (bgh >= 0) && (bgh < H_) && (bgw >= 0) && (bgw < W_);
    const int bghc = min(max(bgh, 0), H_ - 1);
    const int bgwc = min(max(bgw, 0), W_ - 1);
    const float* bptr = f2g + (size_t)b * CHW + (size_t)bghc * W_ + bgwc;
    // ---- A direct-from-global: lane (lp,lg) owns f1[h0+hs][w0+lp], ch 4lg+j ----
    const float* aptr = f1g + (size_t)b * CHW + (size_t)(h0 + hs) * W_ + (w0 + lp)
                            + (size_t)(4 * lg) * HW;
    // stage write base within a chunk-row: [kg][lp=sc&15][tile=sc>>4]
    const int swoff = sr * ROWB + (sc & 15) * 16 + (sc >> 4) * 8;

    float bvr[16], avr[4];
    float bn = 0.f, an = 0.f;
    f16x4 afrag;

    auto issue = [&]() {
#pragma unroll
        for (int j = 0; j < 16; ++j) bvr[j] = bptr[(size_t)j * HW];
#pragma unroll
        for (int j = 0; j < 4; ++j) avr[j] = aptr[(size_t)j * HW];
        bptr += (size_t)KCH * HW;
        aptr += (size_t)KCH * HW;
    };

    auto stage = [&](int buf) {
        unsigned u[8];
#pragma unroll
        for (int q = 0; q < 8; ++q) {
            const float x = bok ? bvr[2 * q] : 0.f;
            const float y = bok ? bvr[2 * q + 1] : 0.f;
            u[q] = pk2(x, y);
            bn = dot2f(u[q], u[q], bn);
        }
        char* dst = lds + buf * BUFB + swoff;
#pragma unroll
        for (int kg = 0; kg < 4; ++kg)
            *reinterpret_cast<uint2*>(dst + kg * 256) = make_uint2(u[2 * kg], u[2 * kg + 1]);
        const unsigned a0 = pk2(avr[0], avr[1]);
        const unsigned a1 = pk2(avr[2], avr[3]);
        an = dot2f(a0, a0, an);
        an = dot2f(a1, a1, an);
        afrag = __builtin_bit_cast(f16x4, make_uint2(a0, a1));
    };

    f32x4 acc[9][2];                    // statically indexed only
#pragma unroll
    for (int dy = 0; dy < 9; ++dy)
#pragma unroll
        for (int bt = 0; bt < 2; ++bt) acc[dy][bt] = (f32x4)0.f;

    const int fro = lg * 256 + lp * 16; // b128 fragment read offset

    auto compute = [&](int buf) {
        __builtin_amdgcn_s_setprio(1);
#pragma unroll
        for (int dy = 0; dy < 9; ++dy) {
            const f16x8 bb = *reinterpret_cast<const f16x8*>(
                lds + buf * BUFB + (hs + dy) * ROWB + fro);
            const f16x4 b0 = __builtin_shufflevector(bb, bb, 0, 1, 2, 3);  // pos lp
            const f16x4 b1 = __builtin_shufflevector(bb, bb, 4, 5, 6, 7);  // pos lp+16
            acc[dy][0] = mfma16(afrag, b0, acc[dy][0]);
            acc[dy][1] = mfma16(afrag, b1, acc[dy][1]);
        }
        __builtin_amdgcn_s_setprio(0);
    };

    // ---- pipeline: double-buffered LDS, ONE raw barrier per chunk,
    //      vmcnt never drained (R12/R17-proven schedule) ----
    issue();                               // ch0 loads
    stage(0);                              // pack+write ch0
    issue();                               // ch1 loads — fly across barrier
    publish_barrier();
    for (int t = 0; t < NCHUNK; t += 2) {
        compute(0);                        // chunk t   (reads buf0)
        stage(1);                          // chunk t+1 (counted-wait its loads)
        if (t + 2 < NCHUNK) issue();       // ch t+2
        publish_barrier();                 // publish buf1; implies buf0 reads done
        compute(1);                        // chunk t+1 (reads buf1)
        if (t + 2 < NCHUNK) {
            stage(0);                      // chunk t+2 (writes buf0 — safe)
            if (t + 3 < NCHUNK) issue();   // ch t+3
        }
        publish_barrier();                 // publish buf0; implies buf1 reads done
    }

    // ---- norms (buffers dead now -> overlay) ----
    float* bnorm = reinterpret_cast<float*>(lds + BNOFF);   // [16][32]
    bnorm[tid] = bn;
    an += __shfl_xor(an, 16);
    an += __shfl_xor(an, 32);                               // full norm of pos lp
    const float inv1own = rsq(fmaxf(an, 1e-24f));
    __syncthreads();

    // ---- pre-scale acc by inv1 (per r) and inv2 (per dy,bt) ----
    {
        const float i0 = __shfl(inv1own, 4 * lg + 0);
        const float i1 = __shfl(inv1own, 4 * lg + 1);
        const float i2 = __shfl(inv1own, 4 * lg + 2);
        const float i3 = __shfl(inv1own, 4 * lg + 3);
#pragma unroll
        for (int dy = 0; dy < 9; ++dy) {
#pragma unroll
            for (int bt = 0; bt < 2; ++bt) {
                const float nb = bnorm[(hs + dy) * BPOS + bt * 16 + lp];
                const float v2 = rsq(fmaxf(nb, 1e-24f));
                acc[dy][bt][0] *= i0 * v2;
                acc[dy][bt][1] *= i1 * v2;
                acc[dy][bt][2] *= i2 * v2;
                acc[dy][bt][3] *= i3 * v2;
            }
        }
    }
    __syncthreads();   // bnorm reads done before out-LDS overlay writes

    // ---- epilogue: two h-half passes through out-LDS (R17-proven, no swizzle) ----
    const size_t obase = (size_t)b * 81 * HW;
#pragma unroll
    for (int pass = 0; pass < 2; ++pass) {
        if ((hs >> 2) == pass) {
            const int h4 = hs & 3;
#pragma unroll
            for (int dy = 0; dy < 9; ++dy) {
#pragma unroll
                for (int bt = 0; bt < 2; ++bt) {
                    const int scol = bt * 16 + lp;                 // staged f2 col
#pragma unroll
                    for (int r = 0; r < 4; ++r) {
                        const int mw  = 4 * lg + r;                // f1 w within tile
                        const int dxi = scol - 4 - mw;             // dx + 4
                        if (dxi >= 0 && dxi <= 8) {
                            const int od = dy * 9 + dxi;
                            float* orow = reinterpret_cast<float*>(lds)
                                        + (od * 4 + h4) * OSTR;
                            orow[mw] = acc[dy][bt][r];
                        }
                    }
                }
            }
        }
        __syncthreads();
        for (int s = tid; s < 81 * 4 * 4; s += NTHREADS) {
            const int od = s >> 4;
            const int rem = s & 15;
            const int h4 = rem >> 2, q = rem & 3;
            const float4 v = *reinterpret_cast<const float4*>(
                reinterpret_cast<const float*>(lds) + (od * 4 + h4) * OSTR + q * 4);
            *reinterpret_cast<float4*>(outg + obase + (size_t)od * HW +
                                       (size_t)(h0 + pass * 4 + h4) * W_ + w0 + q * 4) = v;
        }
        if (pass == 0) __syncthreads();
    }
}

} // namespace

extern "C" void kernel_launch(void* const* d_in, const int* in_sizes, int n_in,
                              void* d_out, int out_size, void* d_ws, size_t ws_size,
                              hipStream_t stream)
{
    (void)in_sizes; (void)n_in; (void)d_ws; (void)ws_size; (void)out_size;
    const float* f1 = (const float*)d_in[0];
    const float* f2 = (const float*)d_in[1];
    float* out = (float*)d_out;

    dim3 grid(1536, 1, 1);     // 8 images x 16 hb x 12 wb, XCD-chunked in kernel
    dim3 block(NTHREADS);      // 512 threads = 8 waves (wave = h row)
    local_corr_mfma<<<grid, block, 0, stream>>>(f1, f2, out);
}